// Round 6
// baseline (3079.068 us; speedup 1.0000x reference)
//
#include <hip/hip_runtime.h>
#include <hip/hip_bf16.h>
#include <hip/hip_fp16.h>

// SVD-RNN: W = U diag(s) V from Householder chains; h_t = tanh(xp_t + W h_{t-1});
// out_t = h_t W_out^T + b_out.
#define BB 64
#define TT 2048
#define II 128
#define HH 256
#define OO 128

// recurrence (MFMA version) params
#define BGRP 16     // batches per workgroup -> 4 WGs
#define RCH 8       // steps per global-I/O chunk
#define NBUF 9      // rotating h buffers (RCH+1: bulk-read/next-write race-free)
#define HPAD 264    // f16 row stride (528 B, 16B-aligned, +8 pad vs 256)

typedef _Float16 f16x2 __attribute__((ext_vector_type(2)));
typedef _Float16 f16x8 __attribute__((ext_vector_type(8)));
typedef float f32x4 __attribute__((ext_vector_type(4)));

#if __has_builtin(__builtin_amdgcn_fdot2)
__device__ __forceinline__ float fdot2(f16x2 a, f16x2 b, float c) {
    return __builtin_amdgcn_fdot2(a, b, c, false);
}
#else
__device__ __forceinline__ float fdot2(f16x2 a, f16x2 b, float c) {
    return fmaf((float)a.x, (float)b.x, fmaf((float)a.y, (float)b.y, c));
}
#endif

__device__ __forceinline__ f16x2 u2h(unsigned int u) { return __builtin_bit_cast(f16x2, u); }
__device__ __forceinline__ unsigned int packf16(float a, float b) {
    return __builtin_bit_cast(unsigned int, f16x2{(_Float16)a, (_Float16)b});
}

__device__ __forceinline__ float tanh_fast(float x) {
    float xc = fminf(fmaxf(x, -9.0f), 9.0f);
    float e = __expf(2.0f * xc);
    return (e - 1.0f) * __fdividef(1.0f, e + 1.0f);
}

// ---------------------------------------------------------------------------
// Kernel 1: masked+flipped Householder vectors and betas.
// ---------------------------------------------------------------------------
__global__ __launch_bounds__(64) void prep_kernel(
    const float* __restrict__ u_raw, const float* __restrict__ v_raw,
    float* __restrict__ u_eff, float* __restrict__ v_eff,
    float* __restrict__ beta_u, float* __restrict__ beta_v)
{
    const int row = blockIdx.x;
    const int lane = threadIdx.x;
    const bool isU = row < HH;
    const int i = isU ? row : row - HH;
    const float* src = isU ? (u_raw + (size_t)i * HH) : (v_raw + (size_t)(HH - 1 - i) * HH);
    float* dst = (isU ? u_eff : v_eff) + (size_t)i * HH;
    const int lo = isU ? (HH - 1 - i) : i;
    float ss = 0.0f;
    for (int c = lane; c < HH; c += 64) {
        float vv = (c >= lo) ? src[HH - 1 - c] : 0.0f;
        dst[c] = vv;
        ss += vv * vv;
    }
    for (int m = 1; m < 64; m <<= 1) ss += __shfl_xor(ss, m, 64);
    if (lane == 0) (isU ? beta_u : beta_v)[i] = 2.0f / ss;
}

// ---------------------------------------------------------------------------
// Kernel 2: Householder chain per column.
// ---------------------------------------------------------------------------
__global__ __launch_bounds__(256) void hh_kernel(
    const float* __restrict__ u_eff, const float* __restrict__ v_eff,
    const float* __restrict__ beta_u, const float* __restrict__ beta_v,
    float* __restrict__ Ucol, float* __restrict__ Vrow)
{
    const int wid = blockIdx.x * 4 + (threadIdx.x >> 6);
    const int lane = threadIdx.x & 63;
    const bool isU = wid < HH;
    const int j = isU ? wid : wid - HH;
    const float* eff = isU ? u_eff : v_eff;
    const float* beta = isU ? beta_u : beta_v;

    float cr0 = (j == 4 * lane + 0) ? 1.0f : 0.0f;
    float cr1 = (j == 4 * lane + 1) ? 1.0f : 0.0f;
    float cr2 = (j == 4 * lane + 2) ? 1.0f : 0.0f;
    float cr3 = (j == 4 * lane + 3) ? 1.0f : 0.0f;

    const int i0 = isU ? (HH - 1 - j) : 0;
    for (int i = i0; i < HH; ++i) {
        const float4 v4 = *(const float4*)(eff + (size_t)i * HH + lane * 4);
        float d = v4.x * cr0 + v4.y * cr1 + v4.z * cr2 + v4.w * cr3;
        for (int m = 1; m < 64; m <<= 1) d += __shfl_xor(d, m, 64);
        const float t = beta[i] * d;
        cr0 = fmaf(-t, v4.x, cr0);
        cr1 = fmaf(-t, v4.y, cr1);
        cr2 = fmaf(-t, v4.z, cr2);
        cr3 = fmaf(-t, v4.w, cr3);
    }
    if (isU) {
        *(float4*)(Ucol + (size_t)j * HH + lane * 4) = make_float4(cr0, cr1, cr2, cr3);
    } else {
        Vrow[(size_t)(4 * lane + 0) * HH + j] = cr0;
        Vrow[(size_t)(4 * lane + 1) * HH + j] = cr1;
        Vrow[(size_t)(4 * lane + 2) * HH + j] = cr2;
        Vrow[(size_t)(4 * lane + 3) * HH + j] = cr3;
    }
}

// ---------------------------------------------------------------------------
// Kernel 3: W[r][c] = sum_k Ucol[k][r] * sig[k] * Vrow[k][c]
// ---------------------------------------------------------------------------
__global__ __launch_bounds__(256) void w_kernel(
    const float* __restrict__ Ucol, const float* __restrict__ Vrow,
    const float* __restrict__ sig, float* __restrict__ Wm)
{
    const int r = blockIdx.x;
    const int c = threadIdx.x;
    float acc = 0.0f;
    #pragma unroll 4
    for (int k = 0; k < HH; ++k) {
        acc = fmaf(Ucol[(size_t)k * HH + r] * sig[k], Vrow[(size_t)k * HH + c], acc);
    }
    Wm[(size_t)r * HH + c] = acc;
}

// ---------------------------------------------------------------------------
// Tiled GEMM with bias, f16x2/dot2 inner: C[M][N] = A[M][K]*B[N][K]^T + bias.
// ---------------------------------------------------------------------------
__device__ __forceinline__ uint4 stage8(const float* p) {
    float4 a = *(const float4*)p;
    float4 b = *(const float4*)(p + 4);
    return make_uint4(packf16(a.x, a.y), packf16(a.z, a.w),
                      packf16(b.x, b.y), packf16(b.z, b.w));
}
__device__ __forceinline__ uint4 stage8(const __half* p) {
    return *(const uint4*)p;
}
__device__ __forceinline__ void storeC(float* p, float v) { *p = v; }
__device__ __forceinline__ void storeC(__half* p, float v) { *p = __float2half_rn(v); }

template <typename AT, typename OT>
__global__ __launch_bounds__(256) void gemm_bias(
    const AT* __restrict__ A, const float* __restrict__ Bm,
    const float* __restrict__ bias, OT* __restrict__ C,
    int M, int N, int K)
{
    __shared__ unsigned int As[64][20];
    __shared__ unsigned int Bs[64][20];
    const int m0 = blockIdx.x * 64;
    const int n0 = blockIdx.y * 64;
    const int tid = threadIdx.x;
    const int lr = tid >> 2;
    const int lc = (tid & 3) << 3;
    const int tm = tid >> 4;
    const int tn = tid & 15;
    float acc[4][4] = {};
    for (int k0 = 0; k0 < K; k0 += 32) {
        *(uint4*)&As[lr][lc >> 1] = stage8(A + (size_t)(m0 + lr) * K + k0 + lc);
        *(uint4*)&Bs[lr][lc >> 1] = stage8(Bm + (size_t)(n0 + lr) * K + k0 + lc);
        __syncthreads();
        #pragma unroll
        for (int k8 = 0; k8 < 4; ++k8) {
            uint4 a4[4], b4[4];
            #pragma unroll
            for (int r = 0; r < 4; ++r) {
                a4[r] = *(const uint4*)&As[tm * 4 + r][k8 * 4];
                b4[r] = *(const uint4*)&Bs[tn + 16 * r][k8 * 4];
            }
            #pragma unroll
            for (int i2 = 0; i2 < 4; ++i2) {
                #pragma unroll
                for (int j2 = 0; j2 < 4; ++j2) {
                    acc[i2][j2] = fdot2(u2h(a4[i2].x), u2h(b4[j2].x), acc[i2][j2]);
                    acc[i2][j2] = fdot2(u2h(a4[i2].y), u2h(b4[j2].y), acc[i2][j2]);
                    acc[i2][j2] = fdot2(u2h(a4[i2].z), u2h(b4[j2].z), acc[i2][j2]);
                    acc[i2][j2] = fdot2(u2h(a4[i2].w), u2h(b4[j2].w), acc[i2][j2]);
                }
            }
        }
        __syncthreads();
    }
    #pragma unroll
    for (int j2 = 0; j2 < 4; ++j2) {
        const int n = n0 + tn + 16 * j2;
        const float bv = bias[n];
        #pragma unroll
        for (int i2 = 0; i2 < 4; ++i2) {
            const int m = m0 + tm * 4 + i2;
            storeC(C + (size_t)m * N + n, acc[i2][j2] + bv);
        }
    }
}

// ---------------------------------------------------------------------------
// Kernel 5 (R5 MFMA restructure): 4 WGs x 16 batches, 512 threads (8 waves).
// Per step: C[j 256][b 16] = W @ h_{t-1} via mfma_f32_16x16x32_f16.
//   A = W tiles (m=j): wave w owns j-tiles 2w,2w+1; frags fixed in regs
//       (A layout: m=lane&15, k=(lane>>4)*8+jj  -- m120-verified).
//   B = h (k=jprev, n=batch): 8x ds_read_b128 from hlds[batch][jprev]
//       (B layout: n=lane&15, k=(lane>>4)*8+jj).
//   C init = xp (free add); D layout: col(n=batch)=lane&15,
//       row(m=j)=(lane>>4)*4+reg -> lane holds 4 CONSECUTIVE j per tile,
//       so tanh+pack -> ONE b64 LDS write per tile.
// MFMA does the K-reduction internally: no cross-wave ps reduce (the
// R0-R4 structure's fixed ~1400cyc/step overhead). ONE barrier/step.
// h buffers rotate over NBUF=9 so the per-chunk coalesced LDS->global bulk
// store of h needs no extra barrier (next chunk's first write hits the
// 9th buffer, outside the chunk's read set).
// xp preloaded per chunk (RCH=8) as b64 (4 halves) per tile per step.
// ---------------------------------------------------------------------------
__global__ __launch_bounds__(512, 2) void recur_mfma(
    const float* __restrict__ Wm,              // [256][256] f32 row-major
    const __half* __restrict__ xp,             // [B][T][256] f16
    __half* __restrict__ hall)                 // [B][T][256] f16
{
    const int bg = blockIdx.x;                 // batch group 0..3
    const int tid = threadIdx.x;
    const int lane = tid & 63;
    const int w = tid >> 6;                    // wave 0..7 -> j tiles 2w,2w+1
    const int lo = lane & 15;
    const int qd = lane >> 4;                  // 0..3

    __shared__ _Float16 hlds[NBUF][BGRP][HPAD];   // 9*16*264*2 = 76032 B

    // A-operand W fragments: tile tt covers j in [16*(2w+tt), +16)
    f16x8 wf[2][8];
    #pragma unroll
    for (int tt = 0; tt < 2; ++tt) {
        const float* wp = Wm + (size_t)(16 * (2 * w + tt) + lo) * HH + qd * 8;
        #pragma unroll
        for (int kb = 0; kb < 8; ++kb) {
            float4 f0 = *(const float4*)(wp + kb * 32);
            float4 f1 = *(const float4*)(wp + kb * 32 + 4);
            wf[tt][kb] = f16x8{(_Float16)f0.x, (_Float16)f0.y, (_Float16)f0.z, (_Float16)f0.w,
                               (_Float16)f1.x, (_Float16)f1.y, (_Float16)f1.z, (_Float16)f1.w};
        }
    }
    // zero the step(-1) h buffer (index NBUF-1)
    for (int i = tid; i < BGRP * HPAD / 2; i += 512)
        ((unsigned int*)&hlds[NBUF - 1][0][0])[i] = 0u;

    const int b_abs = BGRP * bg + lo;          // this lane's batch (n index)
    const __half* xb = xp + (size_t)b_abs * TT * HH;
    const int j0 = 32 * w + 4 * qd;            // tile-0 j base for xp/C rows

    uint2 xpc[2][RCH], xpn[2][RCH];            // xp as 4 packed halves
    #pragma unroll
    for (int s = 0; s < RCH; ++s) {
        xpc[0][s] = *(const uint2*)(xb + (size_t)s * HH + j0);
        xpc[1][s] = *(const uint2*)(xb + (size_t)s * HH + j0 + 16);
    }
    __syncthreads();   // hlds[NBUF-1] zero visible

    const int nch = TT / RCH;                  // 256 chunks
    for (int c = 0; c < nch; ++c) {
        #pragma unroll
        for (int s = 0; s < RCH; ++s) {
            const int gs = c * RCH + s;
            const int rb = (gs + NBUF - 1) % NBUF;   // read buffer (step gs-1)
            const int wb = gs % NBUF;                // write buffer (step gs)
            // prefetch next chunk's xp right after the previous barrier
            if (s == 0 && c + 1 < nch) {
                const __half* xn = xb + (size_t)(c + 1) * RCH * HH;
                #pragma unroll
                for (int s2 = 0; s2 < RCH; ++s2) {
                    xpn[0][s2] = *(const uint2*)(xn + (size_t)s2 * HH + j0);
                    xpn[1][s2] = *(const uint2*)(xn + (size_t)s2 * HH + j0 + 16);
                }
            }
            // B-operand: h_{t-1} fragments (8 KB/wave through LDS)
            f16x8 hb[8];
            const _Float16* hr = &hlds[rb][lo][qd * 8];
            #pragma unroll
            for (int kb = 0; kb < 8; ++kb)
                hb[kb] = *(const f16x8*)(hr + kb * 32);
            // acc init = xp (C operand)
            uint2 xa = xpc[0][s], xbv = xpc[1][s];
            f32x4 acc0 = {(float)u2h(xa.x).x, (float)u2h(xa.x).y,
                          (float)u2h(xa.y).x, (float)u2h(xa.y).y};
            f32x4 acc1 = {(float)u2h(xbv.x).x, (float)u2h(xbv.x).y,
                          (float)u2h(xbv.y).x, (float)u2h(xbv.y).y};
            #pragma unroll
            for (int kb = 0; kb < 8; ++kb) {
                acc0 = __builtin_amdgcn_mfma_f32_16x16x32_f16(wf[0][kb], hb[kb], acc0, 0, 0, 0);
                acc1 = __builtin_amdgcn_mfma_f32_16x16x32_f16(wf[1][kb], hb[kb], acc1, 0, 0, 0);
            }
            // tanh + pack 4 consecutive j per tile -> one b64 LDS write each
            unsigned int p00 = packf16(tanh_fast(acc0.x), tanh_fast(acc0.y));
            unsigned int p01 = packf16(tanh_fast(acc0.z), tanh_fast(acc0.w));
            unsigned int p10 = packf16(tanh_fast(acc1.x), tanh_fast(acc1.y));
            unsigned int p11 = packf16(tanh_fast(acc1.z), tanh_fast(acc1.w));
            *(uint2*)&hlds[wb][lo][j0]      = make_uint2(p00, p01);
            *(uint2*)&hlds[wb][lo][j0 + 16] = make_uint2(p10, p11);
            __syncthreads();   // the one barrier per step
        }
        // bulk store: chunk's h (bufs (c*8..c*8+7)%9) -> hall, coalesced.
        // Race-free: next chunk's first write targets buf (c*8+8)%9.
        {
            const int bb = tid >> 5;          // 0..15
            const int jseg = tid & 31;        // 0..31 (8 f16 each)
            #pragma unroll
            for (int s2 = 0; s2 < RCH; ++s2) {
                const int gs2 = c * RCH + s2;
                uint4 v = *(const uint4*)&hlds[gs2 % NBUF][bb][jseg * 8];
                *(uint4*)(hall + ((size_t)(BGRP * bg + bb) * TT + gs2) * HH + jseg * 8) = v;
            }
        }
        #pragma unroll
        for (int s2 = 0; s2 < RCH; ++s2) {
            xpc[0][s2] = xpn[0][s2];
            xpc[1][s2] = xpn[1][s2];
        }
    }
}

// ---------------------------------------------------------------------------
extern "C" void kernel_launch(void* const* d_in, const int* in_sizes, int n_in,
                              void* d_out, int out_size, void* d_ws, size_t ws_size,
                              hipStream_t stream) {
    const float* x     = (const float*)d_in[0];   // [B][T][I]
    const float* W_in  = (const float*)d_in[1];   // [H][I]
    const float* b_in  = (const float*)d_in[2];   // [H]
    const float* W_out = (const float*)d_in[3];   // [O][H]
    const float* b_out = (const float*)d_in[4];   // [O]
    const float* u_raw = (const float*)d_in[5];   // [M][H]
    const float* sig   = (const float*)d_in[6];   // [H]
    const float* v_raw = (const float*)d_in[7];   // [M][H]
    float* out = (float*)d_out;                   // [B][T][O]

    char* ws = (char*)d_ws;
    size_t off = 0;
    auto alloc = [&](size_t bytes) -> void* {
        void* p = (void*)(ws + off);
        off += (bytes + 255) & ~((size_t)255);
        return p;
    };
    float* u_eff  = (float*)alloc((size_t)HH * HH * 4);
    float* v_eff  = (float*)alloc((size_t)HH * HH * 4);
    float* beta_u = (float*)alloc((size_t)HH * 4);
    float* beta_v = (float*)alloc((size_t)HH * 4);
    float* Ucol   = (float*)alloc((size_t)HH * HH * 4);
    float* Vrow   = (float*)alloc((size_t)HH * HH * 4);
    float* Wm     = (float*)alloc((size_t)HH * HH * 4);
    __half* xpbuf = (__half*)alloc((size_t)BB * TT * HH * 2);
    __half* hall  = (__half*)alloc((size_t)BB * TT * HH * 2);
    (void)ws_size; (void)in_sizes; (void)n_in; (void)out_size;

    prep_kernel<<<2 * HH, 64, 0, stream>>>(u_raw, v_raw, u_eff, v_eff, beta_u, beta_v);
    hh_kernel<<<(2 * HH) / 4, 256, 0, stream>>>(u_eff, v_eff, beta_u, beta_v, Ucol, Vrow);
    w_kernel<<<HH, HH, 0, stream>>>(Ucol, Vrow, sig, Wm);
    gemm_bias<float, __half>
        <<<dim3((BB * TT) / 64, HH / 64), 256, 0, stream>>>(x, W_in, b_in, xpbuf, BB * TT, HH, II);
    recur_mfma<<<BB / BGRP, 512, 0, stream>>>(Wm, xpbuf, hall);
    gemm_bias<__half, float>
        <<<dim3((BB * TT) / 64, OO / 64), 256, 0, stream>>>(hall, W_out, b_out, out, BB * TT, OO, HH);
}

// Round 7
// 1503.675 us; speedup vs baseline: 2.0477x; 2.0477x over previous
//
#include <hip/hip_runtime.h>
#include <hip/hip_bf16.h>
#include <hip/hip_fp16.h>

// SVD-RNN: W = U diag(s) V from Householder chains; h_t = tanh(xp_t + W h_{t-1});
// out_t = h_t W_out^T + b_out.
#define BB 64
#define TT 2048
#define II 128
#define HH 256
#define OO 128
#define RCH 8                      // recurrence chunk length (global I/O batching)

typedef _Float16 f16x2 __attribute__((ext_vector_type(2)));
typedef _Float16 f16x8 __attribute__((ext_vector_type(8)));
typedef float f32x4 __attribute__((ext_vector_type(4)));

#if __has_builtin(__builtin_amdgcn_fdot2)
__device__ __forceinline__ float fdot2(f16x2 a, f16x2 b, float c) {
    return __builtin_amdgcn_fdot2(a, b, c, false);
}
#else
__device__ __forceinline__ float fdot2(f16x2 a, f16x2 b, float c) {
    return fmaf((float)a.x, (float)b.x, fmaf((float)a.y, (float)b.y, c));
}
#endif

__device__ __forceinline__ f16x2 u2h(unsigned int u) { return __builtin_bit_cast(f16x2, u); }
__device__ __forceinline__ unsigned int packf16(float a, float b) {
    return __builtin_bit_cast(unsigned int, f16x2{(_Float16)a, (_Float16)b});
}

__device__ __forceinline__ float tanh_fast(float x) {
    float xc = fminf(fmaxf(x, -9.0f), 9.0f);
    float e = __expf(2.0f * xc);
    return (e - 1.0f) * __fdividef(1.0f, e + 1.0f);
}

// ---------------------------------------------------------------------------
// Kernel 1: masked+flipped Householder vectors and betas.
// ---------------------------------------------------------------------------
__global__ __launch_bounds__(64) void prep_kernel(
    const float* __restrict__ u_raw, const float* __restrict__ v_raw,
    float* __restrict__ u_eff, float* __restrict__ v_eff,
    float* __restrict__ beta_u, float* __restrict__ beta_v)
{
    const int row = blockIdx.x;
    const int lane = threadIdx.x;
    const bool isU = row < HH;
    const int i = isU ? row : row - HH;
    const float* src = isU ? (u_raw + (size_t)i * HH) : (v_raw + (size_t)(HH - 1 - i) * HH);
    float* dst = (isU ? u_eff : v_eff) + (size_t)i * HH;
    const int lo = isU ? (HH - 1 - i) : i;
    float ss = 0.0f;
    for (int c = lane; c < HH; c += 64) {
        float vv = (c >= lo) ? src[HH - 1 - c] : 0.0f;
        dst[c] = vv;
        ss += vv * vv;
    }
    for (int m = 1; m < 64; m <<= 1) ss += __shfl_xor(ss, m, 64);
    if (lane == 0) (isU ? beta_u : beta_v)[i] = 2.0f / ss;
}

// ---------------------------------------------------------------------------
// Kernel 2: Householder chain per column.
// ---------------------------------------------------------------------------
__global__ __launch_bounds__(256) void hh_kernel(
    const float* __restrict__ u_eff, const float* __restrict__ v_eff,
    const float* __restrict__ beta_u, const float* __restrict__ beta_v,
    float* __restrict__ Ucol, float* __restrict__ Vrow)
{
    const int wid = blockIdx.x * 4 + (threadIdx.x >> 6);
    const int lane = threadIdx.x & 63;
    const bool isU = wid < HH;
    const int j = isU ? wid : wid - HH;
    const float* eff = isU ? u_eff : v_eff;
    const float* beta = isU ? beta_u : beta_v;

    float cr0 = (j == 4 * lane + 0) ? 1.0f : 0.0f;
    float cr1 = (j == 4 * lane + 1) ? 1.0f : 0.0f;
    float cr2 = (j == 4 * lane + 2) ? 1.0f : 0.0f;
    float cr3 = (j == 4 * lane + 3) ? 1.0f : 0.0f;

    const int i0 = isU ? (HH - 1 - j) : 0;
    for (int i = i0; i < HH; ++i) {
        const float4 v4 = *(const float4*)(eff + (size_t)i * HH + lane * 4);
        float d = v4.x * cr0 + v4.y * cr1 + v4.z * cr2 + v4.w * cr3;
        for (int m = 1; m < 64; m <<= 1) d += __shfl_xor(d, m, 64);
        const float t = beta[i] * d;
        cr0 = fmaf(-t, v4.x, cr0);
        cr1 = fmaf(-t, v4.y, cr1);
        cr2 = fmaf(-t, v4.z, cr2);
        cr3 = fmaf(-t, v4.w, cr3);
    }
    if (isU) {
        *(float4*)(Ucol + (size_t)j * HH + lane * 4) = make_float4(cr0, cr1, cr2, cr3);
    } else {
        Vrow[(size_t)(4 * lane + 0) * HH + j] = cr0;
        Vrow[(size_t)(4 * lane + 1) * HH + j] = cr1;
        Vrow[(size_t)(4 * lane + 2) * HH + j] = cr2;
        Vrow[(size_t)(4 * lane + 3) * HH + j] = cr3;
    }
}

// ---------------------------------------------------------------------------
// Kernel 3: W[r][c] = sum_k Ucol[k][r] * sig[k] * Vrow[k][c]
// ---------------------------------------------------------------------------
__global__ __launch_bounds__(256) void w_kernel(
    const float* __restrict__ Ucol, const float* __restrict__ Vrow,
    const float* __restrict__ sig, float* __restrict__ Wm)
{
    const int r = blockIdx.x;
    const int c = threadIdx.x;
    float acc = 0.0f;
    #pragma unroll 4
    for (int k = 0; k < HH; ++k) {
        acc = fmaf(Ucol[(size_t)k * HH + r] * sig[k], Vrow[(size_t)k * HH + c], acc);
    }
    Wm[(size_t)r * HH + c] = acc;
}

// ---------------------------------------------------------------------------
// MFMA tiled GEMM with bias: C[M][N] = A[M][K] * B[N][K]^T + bias[N].
// BM=128, BN=64, BK=32; 256 threads = 4 waves, each wave a 64x32 quadrant
// (4 m-tiles x 2 n-tiles of 16x16, mfma_f32_16x16x32_f16).
// LDS rows padded to 40 f16 (80 B): frag-read bank group = (5*row+qd) mod 8
// -> all 8 groups per 8 lanes, worst 2-way (free). Layout conventions
// (A: m=lane&15,k=(lane>>4)*8+i; B: n=lane&15,same k; D: col=lane&15,
// row=(lane>>4)*4+reg) are hardware-validated by the R5 recur kernel.
// ---------------------------------------------------------------------------
__device__ __forceinline__ void stage16(_Float16* dst, const float* src) {
    #pragma unroll
    for (int i = 0; i < 4; ++i) {
        float4 f = ((const float4*)src)[i];
        ((f16x2*)dst)[2 * i + 0] = f16x2{(_Float16)f.x, (_Float16)f.y};
        ((f16x2*)dst)[2 * i + 1] = f16x2{(_Float16)f.z, (_Float16)f.w};
    }
}
__device__ __forceinline__ void stage16(_Float16* dst, const __half* src) {
    ((uint4*)dst)[0] = ((const uint4*)src)[0];
    ((uint4*)dst)[1] = ((const uint4*)src)[1];
}
__device__ __forceinline__ void storeC(float* p, float v) { *p = v; }
__device__ __forceinline__ void storeC(__half* p, float v) { *p = __float2half_rn(v); }

template <typename AT, typename OT>
__global__ __launch_bounds__(256) void gemm_mfma(
    const AT* __restrict__ A, const float* __restrict__ Bm,
    const float* __restrict__ bias, OT* __restrict__ C,
    int M, int N, int K)
{
    __shared__ _Float16 As[128][40];
    __shared__ _Float16 Bs[64][40];
    const int tid = threadIdx.x;
    const int m0 = blockIdx.x * 128;
    const int n0 = blockIdx.y * 64;
    const int lane = tid & 63;
    const int w = tid >> 6;
    const int lo = lane & 15;
    const int qd = lane >> 4;
    const int mh = w >> 1;               // m-half (64 rows)
    const int nh = w & 1;                // n-half (32 cols)
    const int srow = tid >> 1;           // staging row 0..127
    const int shalf = tid & 1;           // 16-f16 half of the 32-k row

    f32x4 acc[4][2] = {};
    for (int k0 = 0; k0 < K; k0 += 32) {
        stage16(&As[srow][shalf * 16], A + (size_t)(m0 + srow) * K + k0 + shalf * 16);
        if (tid < 128)
            stage16(&Bs[srow][shalf * 16], Bm + (size_t)(n0 + srow) * K + k0 + shalf * 16);
        __syncthreads();
        f16x8 af[4], bf[2];
        #pragma unroll
        for (int mt = 0; mt < 4; ++mt)
            af[mt] = *(const f16x8*)&As[64 * mh + 16 * mt + lo][qd * 8];
        #pragma unroll
        for (int nt = 0; nt < 2; ++nt)
            bf[nt] = *(const f16x8*)&Bs[32 * nh + 16 * nt + lo][qd * 8];
        #pragma unroll
        for (int mt = 0; mt < 4; ++mt)
            #pragma unroll
            for (int nt = 0; nt < 2; ++nt)
                acc[mt][nt] = __builtin_amdgcn_mfma_f32_16x16x32_f16(
                    af[mt], bf[nt], acc[mt][nt], 0, 0, 0);
        __syncthreads();
    }
    #pragma unroll
    for (int nt = 0; nt < 2; ++nt) {
        const int n = n0 + 32 * nh + 16 * nt + lo;
        const float bv = bias[n];
        #pragma unroll
        for (int mt = 0; mt < 4; ++mt) {
            const int m = m0 + 64 * mh + 16 * mt + 4 * qd;
            #pragma unroll
            for (int r = 0; r < 4; ++r)
                storeC(C + (size_t)(m + r) * N + n, acc[mt][nt][r] + bv);
        }
    }
}

// ---------------------------------------------------------------------------
// Kernel 5: recurrence (R3/R4-proven, 1179 us). 64 WGs x 512 threads (8 waves).
// Wave q owns k-slice [q*32,q*32+32); lane l owns rows 4l..4l+3. W fragment in
// registers as f16x2 (v_dot2_f32_f16). Per step: phase1 (4 uniform b128 h
// reads + 64 dot2 + 1 b128 ps write), barrier, phase2 (tid<128: 8 b64 ps
// reads + xp + 2x tanh + hbuf write), barrier. Global I/O CHUNKED (RCH=8).
// NO LDS atomics (R1: same-address ds atomics serialize, 8.6x regression).
// R5's single-barrier readlane variant and R6's MFMA variant both measured
// SLOWER (1237 / 2677 us) — keep this shape.
// ---------------------------------------------------------------------------
__global__ __launch_bounds__(512) void recur_kernel(
    const float* __restrict__ Wm,              // [256][256] f32 row-major
    const __half* __restrict__ xp,             // [B][T][256] f16
    __half* __restrict__ hall)                 // [B][T][256] f16
{
    const int b = blockIdx.x;
    const int tid = threadIdx.x;
    const int l = tid & 63;
    const int q = tid >> 6;        // wave 0..7

    __shared__ float ps[8][HH];                // partial sums, 8 KB
    __shared__ unsigned int hbits[2][HH / 2];  // h as packed f16x2, 1 KB

    // W fragment: rows 4l..4l+3, cols q*32..q*32+32, as f16 pairs (64 VGPRs).
    f16x2 w2[4][16];
    #pragma unroll
    for (int r = 0; r < 4; ++r) {
        const float* Wp = Wm + (size_t)(4 * l + r) * HH + q * 32;
        #pragma unroll
        for (int c4 = 0; c4 < 8; ++c4) {
            float4 f = *(const float4*)(Wp + c4 * 4);
            w2[r][c4 * 2 + 0] = f16x2{(_Float16)f.x, (_Float16)f.y};
            w2[r][c4 * 2 + 1] = f16x2{(_Float16)f.z, (_Float16)f.w};
        }
    }
    if (tid < HH / 2) hbits[0][tid] = 0u;
    __syncthreads();

    const unsigned int* xpw = (const unsigned int*)(xp + (size_t)b * TT * HH);
    unsigned int* hw = (unsigned int*)(hall + (size_t)b * TT * HH);

    unsigned int xpcur[RCH], xpnxt[RCH], hst[RCH];
    if (tid < 128) {
        #pragma unroll
        for (int s = 0; s < RCH; ++s) xpcur[s] = xpw[(size_t)s * 128 + tid];
    }

    const int nch = TT / RCH;
    for (int c = 0; c < nch; ++c) {
        #pragma unroll
        for (int s = 0; s < RCH; ++s) {
            const int p = s & 1;
            if (s == 0 && tid < 128 && c + 1 < nch) {
                const unsigned int* xn = xpw + (size_t)(c + 1) * RCH * 128 + tid;
                #pragma unroll
                for (int s2 = 0; s2 < RCH; ++s2) xpnxt[s2] = xn[(size_t)s2 * 128];
            }
            uint4 ha = *(const uint4*)&hbits[p][q * 16 + 0];
            uint4 hc = *(const uint4*)&hbits[p][q * 16 + 4];
            uint4 hd = *(const uint4*)&hbits[p][q * 16 + 8];
            uint4 he = *(const uint4*)&hbits[p][q * 16 + 12];
            f16x2 hv[16] = {
                u2h(ha.x), u2h(ha.y), u2h(ha.z), u2h(ha.w),
                u2h(hc.x), u2h(hc.y), u2h(hc.z), u2h(hc.w),
                u2h(hd.x), u2h(hd.y), u2h(hd.z), u2h(hd.w),
                u2h(he.x), u2h(he.y), u2h(he.z), u2h(he.w)};
            float a0 = 0.f, a1 = 0.f, a2 = 0.f, a3 = 0.f;
            #pragma unroll
            for (int cc = 0; cc < 16; ++cc) {
                a0 = fdot2(w2[0][cc], hv[cc], a0);
                a1 = fdot2(w2[1][cc], hv[cc], a1);
                a2 = fdot2(w2[2][cc], hv[cc], a2);
                a3 = fdot2(w2[3][cc], hv[cc], a3);
            }
            *(float4*)(&ps[q][4 * l]) = make_float4(a0, a1, a2, a3);
            __syncthreads();

            if (tid < 128) {
                float sx = 0.f, sy = 0.f;
                #pragma unroll
                for (int qq = 0; qq < 8; ++qq) {
                    float2 v = *(const float2*)&ps[qq][2 * tid];
                    sx += v.x; sy += v.y;
                }
                f16x2 xv = u2h(xpcur[s]);
                float h0 = tanh_fast(sx + (float)xv.x);
                float h1 = tanh_fast(sy + (float)xv.y);
                unsigned int hb2 = packf16(h0, h1);
                hbits[p ^ 1][tid] = hb2;
                hst[s] = hb2;
            }
            __syncthreads();
        }
        if (tid < 128) {
            unsigned int* hwc = hw + (size_t)c * RCH * 128 + tid;
            #pragma unroll
            for (int s = 0; s < RCH; ++s) hwc[(size_t)s * 128] = hst[s];
            #pragma unroll
            for (int s = 0; s < RCH; ++s) xpcur[s] = xpnxt[s];
        }
    }
}

// ---------------------------------------------------------------------------
extern "C" void kernel_launch(void* const* d_in, const int* in_sizes, int n_in,
                              void* d_out, int out_size, void* d_ws, size_t ws_size,
                              hipStream_t stream) {
    const float* x     = (const float*)d_in[0];   // [B][T][I]
    const float* W_in  = (const float*)d_in[1];   // [H][I]
    const float* b_in  = (const float*)d_in[2];   // [H]
    const float* W_out = (const float*)d_in[3];   // [O][H]
    const float* b_out = (const float*)d_in[4];   // [O]
    const float* u_raw = (const float*)d_in[5];   // [M][H]
    const float* sig   = (const float*)d_in[6];   // [H]
    const float* v_raw = (const float*)d_in[7];   // [M][H]
    float* out = (float*)d_out;                   // [B][T][O]

    char* ws = (char*)d_ws;
    size_t off = 0;
    auto alloc = [&](size_t bytes) -> void* {
        void* p = (void*)(ws + off);
        off += (bytes + 255) & ~((size_t)255);
        return p;
    };
    float* u_eff  = (float*)alloc((size_t)HH * HH * 4);
    float* v_eff  = (float*)alloc((size_t)HH * HH * 4);
    float* beta_u = (float*)alloc((size_t)HH * 4);
    float* beta_v = (float*)alloc((size_t)HH * 4);
    float* Ucol   = (float*)alloc((size_t)HH * HH * 4);
    float* Vrow   = (float*)alloc((size_t)HH * HH * 4);
    float* Wm     = (float*)alloc((size_t)HH * HH * 4);
    __half* xpbuf = (__half*)alloc((size_t)BB * TT * HH * 2);
    __half* hall  = (__half*)alloc((size_t)BB * TT * HH * 2);
    (void)ws_size; (void)in_sizes; (void)n_in; (void)out_size;

    prep_kernel<<<2 * HH, 64, 0, stream>>>(u_raw, v_raw, u_eff, v_eff, beta_u, beta_v);
    hh_kernel<<<(2 * HH) / 4, 256, 0, stream>>>(u_eff, v_eff, beta_u, beta_v, Ucol, Vrow);
    w_kernel<<<HH, HH, 0, stream>>>(Ucol, Vrow, sig, Wm);
    gemm_mfma<float, __half>
        <<<dim3((BB * TT) / 128, HH / 64), 256, 0, stream>>>(x, W_in, b_in, xpbuf, BB * TT, HH, II);
    recur_kernel<<<BB, 512, 0, stream>>>(Wm, xpbuf, hall);
    gemm_mfma<__half, float>
        <<<dim3((BB * TT) / 128, OO / 64), 256, 0, stream>>>(hall, W_out, b_out, out, BB * TT, OO, HH);
}